// Round 6
// baseline (382.272 us; speedup 1.0000x reference)
//
#include <hip/hip_runtime.h>
#include <cmath>
#include <stdint.h>

#define HH 64
#define WD 64
#define CIN 256
#define COUT 256
#define NB 32

typedef _Float16 half8 __attribute__((ext_vector_type(8)));
typedef _Float16 half4 __attribute__((ext_vector_type(4)));
typedef float floatx4 __attribute__((ext_vector_type(4)));
typedef float floatx16 __attribute__((ext_vector_type(16)));

#define SB() __builtin_amdgcn_sched_barrier(0)

__device__ __forceinline__ void glds16(const void* src, void* dst) {
    __builtin_amdgcn_global_load_lds((const __attribute__((address_space(1))) void*)src,
                                     (__attribute__((address_space(3))) void*)dst, 16, 0, 0);
}

// x16 lives in the LOWER half of each 16KB plane slot of d_out.
// Linear x16 byte offset B (in [0, 64Mi)) maps to d_out byte M = B + (B & ~8191).
__device__ __forceinline__ unsigned xmap(unsigned B) {
    return B + (B & 0xFFFFE000u);
}

// ---------------------------------------------------------------------------
// Fused prep: blocks [0,16384) xprep, [16384,18688) wprep, [18688,18944) gprep.
//
// xprep (LDS-free): thread (kc,wq) gathers 8 fp32 at channel stride (each
// j-step is a coalesced 64B-granule wave read), packs half8, writes 16B into
// a contiguous-per-wave 1KB run of the d_out lower halves.
// wprep: w [co][ci][3][3] fp32 -> fp16 [chunk8][cb4][tap9][u4][q4][m16][j8]
// gprep: circulant generators + expansion to swizzled fp16 matrices
// ---------------------------------------------------------------------------
__global__ __launch_bounds__(256) void prep_kernel(const float* __restrict__ x,
                                                   const float* __restrict__ w,
                                                   const float* __restrict__ alpha,
                                                   float* __restrict__ y,
                                                   _Float16* __restrict__ w16,
                                                   _Float16* __restrict__ gm,
                                                   float4* __restrict__ zp) {
    __shared__ float gl[128];
    const int tid = threadIdx.x;
    const int bb = blockIdx.x;

    if (bb < 16384) {
        // ---------------- xprep (no LDS, no barrier) ----------------
        const int h = bb & 63;
        const int chunk = (bb >> 6) & 7;
        const int n = bb >> 9;
        const int kc = tid & 3;
        const int wq = tid >> 2;
        const float* src = x + (((size_t)(n * 256 + chunk * 32 + kc * 8) * 64 + h) * 64 + wq);
        half8 hv;
        #pragma unroll
        for (int j = 0; j < 8; ++j) hv[j] = (_Float16)src[j * 4096];
        const unsigned L = ((((unsigned)(n * 8 + chunk) * 64 + h) * 64 + wq) * 32 + kc * 8);
        *(half8*)((char*)y + xmap(L * 2u)) = hv;
    } else if (bb < 16384 + 2304) {
        // ---------------- wprep ----------------
        const int idx = (bb - 16384) * 256 + tid;   // 589,824
        const int j = idx & 7;
        const int m = (idx >> 3) & 15;
        const int q = (idx >> 7) & 3;
        const int u = (idx >> 9) & 3;
        const int rest = idx >> 11;
        const int tap = rest % 9;
        const int rr = rest / 9;
        const int cb = rr & 3;
        const int chunk = rr >> 2;
        const int co = cb * 64 + u * 16 + m;
        const int ci = chunk * 32 + q * 8 + j;
        w16[idx] = (_Float16)w[(co * CIN + ci) * 9 + tap];
        if (bb == 16384) {
            float4 z; z.x = 0.f; z.y = 0.f; z.z = 0.f; z.w = 0.f;
            zp[tid] = z;   // 4 KB of zeros
        }
    } else {
        // ---------------- gprep ----------------
        const int c = bb - 18688;     // 0..255
        if (tid < 128) {
            const int r   = tid & 63;
            const int isv = tid >> 6;
            const float t0 = tanhf(alpha[c * 4 + isv * 2 + 0]);
            const float t1 = tanhf(alpha[c * 4 + isv * 2 + 1]);
            const float qq = 0.70710678118654752f;
            const float a0 = qq * (t0 + t1);   // tap -1
            const float a2 = qq * (t1 - t0);   // tap +1
            const float rev = 0.015625f;       // 1/64 revolution
            float ssum = 0.f;
            for (int p = 0; p < 64; ++p) {
                const float pr = (float)p * rev;
                const float re = 1.f + (a0 + a2) * __builtin_amdgcn_cosf(pr);
                const float im = (a0 - a2) * __builtin_amdgcn_sinf(pr);
                const float inv = 1.f / (re * re + im * im);
                const float ph = (float)((p * r) & 63) * rev;
                ssum += (__builtin_amdgcn_cosf(ph) * re + __builtin_amdgcn_sinf(ph) * im) * inv;
            }
            gl[tid] = ssum * (1.0f / 64.0f);
        }
        __syncthreads();
        #pragma unroll
        for (int it = 0; it < 4; ++it) {
            const int idx = it * 256 + tid;   // 0..1023 = which*512 + row*8 + kc
            const int kc = idx & 7;
            const int row = (idx >> 3) & 63;
            const int which = idx >> 9;
            const float* g = gl + which * 64;
            half8 hv;
            #pragma unroll
            for (int j = 0; j < 8; ++j)
                hv[j] = (_Float16)g[(row - (kc * 8 + j)) & 63];
            *(half8*)&gm[((size_t)(c * 2 + which) * 64 + row) * 64 + ((kc ^ (row & 7)) * 8)] = hv;
        }
    }
}

// ---------------------------------------------------------------------------
// Conv 3x3 as implicit GEMM, fp16 MFMA 16x16x32 (verified 122 us core).
// UNCHANGED from round 5.
// ---------------------------------------------------------------------------
__global__ __launch_bounds__(256, 2) void conv_mfma(const _Float16* __restrict__ w16,
                                                    const _Float16* __restrict__ zp,
                                                    float* __restrict__ y) {
    extern __shared__ __align__(16) _Float16 xs2[];   // 2 * 19,584 halfs = 78,336 B
    const int tid  = threadIdx.x;
    const int lane = tid & 63;
    const int wv   = tid >> 6;          // 0..3
    const int m    = lane & 15;
    const int q    = lane >> 4;

    // XCD-bijective remap: the 8 (cb,wt) blocks of one (n,ht) land on one XCD.
    const int bid  = blockIdx.x;        // 1024
    const int xcd  = bid & 7;
    const int idx  = bid >> 3;          // 0..127
    const int sub  = idx & 7;
    const int cb   = sub >> 1;          // 0..3
    const int wt   = sub & 1;           // 0..1
    const int pair = xcd * 16 + (idx >> 3);   // 0..127 = (ht,n)
    const int ht   = pair & 3;
    const int n    = pair >> 2;
    const int h0   = ht * 16;
    const int w0   = wt * 32;

    // staging: 2448 slots of 16B; slot = row*136 + col*4 + octp (rows 18, cols 34)
    // stored data = x[h0-1+row][w0-1+col][oct = octp ^ (col&3)]  (pre-swizzled src)
    int soffB[10];
    #pragma unroll
    for (int it = 0; it < 10; ++it) {
        const int slot = it * 256 + tid;
        const int row  = (slot * 7711) >> 20;        // floor(slot/136), slot<2448
        const int rem  = slot - row * 136;
        const int col  = rem >> 2;
        const int oct  = (rem & 3) ^ (col & 3);
        const int gh   = h0 - 1 + row;
        const int gw   = w0 - 1 + col;
        soffB[it] = ((unsigned)gh < 64u && (unsigned)gw < 64u)
                 ? (((gh * 64 + gw) * 32 + oct * 8) * 2) : -1;
    }

    // per-lane af column offset (halfs) per kx within (row, cbk=0)
    int aoff[3];
    #pragma unroll
    for (int kx = 0; kx < 3; ++kx)
        aoff[kx] = (m + kx) * 32 + ((q ^ ((m + kx) & 3)) * 8);

    floatx4 acc[4][2][4];
    #pragma unroll
    for (int ro = 0; ro < 4; ++ro)
        #pragma unroll
        for (int cbk = 0; cbk < 2; ++cbk)
            #pragma unroll
            for (int u = 0; u < 4; ++u) acc[ro][cbk][u] = (floatx4)0.f;

    const char* yb = (const char*)y;

    // prologue: stage chunk 0 into buffer 0
    {
        const unsigned cbb0 = (unsigned)n * 2097152u;   // (n*8+0)*262144 bytes
        #pragma unroll
        for (int it = 0; it < 10; ++it) {
            if (it * 256 + tid < 2448) {
                const void* src = (soffB[it] >= 0)
                    ? (const void*)(yb + xmap(cbb0 + (unsigned)soffB[it]))
                    : (const void*)(zp + (lane << 3));
                glds16(src, xs2 + (size_t)(it * 256 + wv * 64) * 8);
            }
        }
    }
    asm volatile("s_waitcnt vmcnt(0)" ::: "memory");
    __syncthreads();

    for (int c = 0; c < 8; ++c) {
        _Float16* bcur = xs2 + (c & 1) * 19584;
        _Float16* bnxt = xs2 + ((c & 1) ^ 1) * 19584;
        const _Float16* wchunk = w16 + (size_t)(c * 4 + cb) * 18432;
        const unsigned cbbn = (unsigned)(n * 8 + c + 1) * 262144u;  // next-chunk byte base
        const bool pf = (c < 7);

        #pragma unroll
        for (int kx = 0; kx < 3; ++kx) {
            half8 bf[3][4];
            #pragma unroll
            for (int ky = 0; ky < 3; ++ky)
                #pragma unroll
                for (int u = 0; u < 4; ++u)
                    bf[ky][u] = *(const half8*)&wchunk[(ky * 3 + kx) * 2048 + u * 512 + lane * 8];

            // early-issued staging of next chunk (5 iters after kx0, 5 after kx1)
            if (kx == 0 && pf) {
                SB();
                #pragma unroll
                for (int it = 0; it < 5; ++it) {
                    const void* src = (soffB[it] >= 0)
                        ? (const void*)(yb + xmap(cbbn + (unsigned)soffB[it]))
                        : (const void*)(zp + (lane << 3));
                    glds16(src, bnxt + (size_t)(it * 256 + wv * 64) * 8);
                }
                SB();
            }
            if (kx == 1 && pf) {
                SB();
                #pragma unroll
                for (int it = 5; it < 10; ++it) {
                    if (it * 256 + tid < 2448) {
                        const void* src = (soffB[it] >= 0)
                            ? (const void*)(yb + xmap(cbbn + (unsigned)soffB[it]))
                            : (const void*)(zp + (lane << 3));
                        glds16(src, bnxt + (size_t)(it * 256 + wv * 64) * 8);
                    }
                }
                SB();
            }

            #pragma unroll
            for (int cbk = 0; cbk < 2; ++cbk) {
                half8 af[6];
                #pragma unroll
                for (int rr = 0; rr < 6; ++rr)
                    af[rr] = *(const half8*)&bcur[(wv * 4 + rr) * 1088 + cbk * 512 + aoff[kx]];
                __builtin_amdgcn_s_setprio(1);
                #pragma unroll
                for (int ro = 0; ro < 4; ++ro)
                    #pragma unroll
                    for (int ky = 0; ky < 3; ++ky)
                        #pragma unroll
                        for (int u = 0; u < 4; ++u)
                            acc[ro][cbk][u] = __builtin_amdgcn_mfma_f32_16x16x32_f16(
                                bf[ky][u], af[ro + ky], acc[ro][cbk][u], 0, 0, 0);
                __builtin_amdgcn_s_setprio(0);
            }
        }
        asm volatile("s_waitcnt vmcnt(0)" ::: "memory");
        __syncthreads();
    }

    // epilogue: fp16 y into upper half of each plane's 16KB slot in d_out
    _Float16* y16o = (_Float16*)y;
    #pragma unroll
    for (int u = 0; u < 4; ++u) {
        #pragma unroll
        for (int r = 0; r < 4; ++r) {
            const int co = cb * 64 + u * 16 + q * 4 + r;
            _Float16* yp = y16o + (size_t)(n * COUT + co) * 8192 + 4096;
            #pragma unroll
            for (int ro = 0; ro < 4; ++ro)
                #pragma unroll
                for (int cbk = 0; cbk < 2; ++cbk)
                    yp[(h0 + wv * 4 + ro) * 64 + w0 + cbk * 16 + m] = (_Float16)acc[ro][cbk][u][r];
        }
    }
}

// ---------------------------------------------------------------------------
// Solve v3: Out = Gu * (Y * Gv^T), one wave per plane, K of GEMM2 split into
// two 32-row halves so the transpose buffer TT is 4KB/wave (LDS 32KB total
// -> 4 blocks/CU).  yf0 issued before the G barrier; yf1 issued under
// GEMM2-half0.  Wave-local lgkmcnt(0)+sched_barrier sync only.
// ---------------------------------------------------------------------------
__global__ __launch_bounds__(256, 4) void solve_mfma(const _Float16* __restrict__ gm,
                                                     float* __restrict__ y) {
    __shared__ __align__(16) _Float16 Gsh[2 * 64 * 64];   // 16 KB (Gu, Gv; swizzled)
    __shared__ __align__(16) _Float16 TT[4][32 * 64];     // 4 KB per wave
    const int tid  = threadIdx.x;
    const int lane = tid & 63;
    const int wv   = tid >> 6;
    const int l31  = lane & 31;
    const int kh   = lane >> 5;

    // XCD-major remap: the 8 nq-blocks of one c land on one XCD (G reuse in L2)
    const int bid = blockIdx.x;                 // 2048
    const int wg  = (bid & 7) * 256 + (bid >> 3);
    const int c   = wg >> 3;
    const int nq  = wg & 7;
    const int n   = nq * 4 + wv;                // this wave's plane

    // stage G (both matrices, swizzled layout preserved, linear copy)
    {
        const _Float16* gsrc = gm + (size_t)c * 8192;
        #pragma unroll
        for (int it = 0; it < 4; ++it)
            glds16(gsrc + (size_t)(it * 256 + tid) * 8, Gsh + (size_t)(it * 256 + wv * 64) * 8);
    }
    const _Float16* ysrc = (const _Float16*)y + ((size_t)n * 256 + c) * 8192 + 4096;
    float* yp = y + ((size_t)n * 256 + c) * 4096;
    _Float16* tt = TT[wv];

    // preload yf0 (Y rows 0..31) before the barrier — drains with the G stage
    half8 yf0[4];
    #pragma unroll
    for (int ks = 0; ks < 4; ++ks)
        yf0[ks] = *(const half8*)&ysrc[l31 * 64 + ks * 16 + kh * 8];

    asm volatile("s_waitcnt vmcnt(0)" ::: "memory");
    __syncthreads();

    floatx16 a2[2][2];
    #pragma unroll
    for (int tr = 0; tr < 2; ++tr)
        #pragma unroll
        for (int tc = 0; tc < 2; ++tc) a2[tr][tc] = (floatx16)0.f;

    // ================= half 0: T rows [0,32) =================
    {
        floatx16 a1[2];
        a1[0] = (floatx16)0.f; a1[1] = (floatx16)0.f;
        #pragma unroll
        for (int ks = 0; ks < 4; ++ks) {
            const int kc = ks * 2 + kh;
            half8 gv[2];
            #pragma unroll
            for (int tc = 0; tc < 2; ++tc) {
                const int row = 32 * tc + l31;
                gv[tc] = *(const half8*)&Gsh[4096 + row * 64 + ((kc ^ (row & 7)) * 8)];
            }
            __builtin_amdgcn_s_setprio(1);
            #pragma unroll
            for (int tc = 0; tc < 2; ++tc)
                a1[tc] = __builtin_amdgcn_mfma_f32_32x32x16_f16(yf0[ks], gv[tc], a1[tc], 0, 0, 0);
            __builtin_amdgcn_s_setprio(0);
        }
        // write T rows [0,32): row' = (reg&3) + 8*q2 + 4*kh; group q2, j = rq+4kh
        #pragma unroll
        for (int tc = 0; tc < 2; ++tc) {
            const int col = 32 * tc + l31;
            #pragma unroll
            for (int q2 = 0; q2 < 4; ++q2) {
                half4 hv;
                #pragma unroll
                for (int rq = 0; rq < 4; ++rq) hv[rq] = (_Float16)a1[tc][q2 * 4 + rq];
                *(half4*)&tt[col * 32 + ((q2 ^ (col & 3)) * 8) + 4 * kh] = hv;
            }
        }
    }
    // issue yf1 (Y rows 32..63) — latency hides under GEMM2-half0
    half8 yf1[4];
    #pragma unroll
    for (int ks = 0; ks < 4; ++ks)
        yf1[ks] = *(const half8*)&ysrc[(32 + l31) * 64 + ks * 16 + kh * 8];

    asm volatile("s_waitcnt lgkmcnt(0)" ::: "memory");
    SB();
    // GEMM2 half0: k groups 0..3 (global Gu k-groups 0..3)
    #pragma unroll
    for (int ks2 = 0; ks2 < 2; ++ks2) {
        const int kc2 = ks2 * 2 + kh;       // 0..3
        half8 gu[2], tb[2];
        #pragma unroll
        for (int tr = 0; tr < 2; ++tr) {
            const int row = 32 * tr + l31;
            gu[tr] = *(const half8*)&Gsh[row * 64 + ((kc2 ^ (row & 7)) * 8)];
        }
        #pragma unroll
        for (int tc = 0; tc < 2; ++tc) {
            const int col = 32 * tc + l31;
            tb[tc] = *(const half8*)&tt[col * 32 + ((kc2 ^ (col & 3)) * 8)];
        }
        __builtin_amdgcn_s_setprio(1);
        #pragma unroll
        for (int tr = 0; tr < 2; ++tr)
            #pragma unroll
            for (int tc = 0; tc < 2; ++tc)
                a2[tr][tc] = __builtin_amdgcn_mfma_f32_32x32x16_f16(gu[tr], tb[tc], a2[tr][tc], 0, 0, 0);
        __builtin_amdgcn_s_setprio(0);
    }

    // ================= half 1: T rows [32,64) =================
    {
        floatx16 a1[2];
        a1[0] = (floatx16)0.f; a1[1] = (floatx16)0.f;
        asm volatile("s_waitcnt vmcnt(0)" ::: "memory");   // yf1 ready
        #pragma unroll
        for (int ks = 0; ks < 4; ++ks) {
            const int kc = ks * 2 + kh;
            half8 gv[2];
            #pragma unroll
            for (int tc = 0; tc < 2; ++tc) {
                const int row = 32 * tc + l31;
                gv[tc] = *(const half8*)&Gsh[4096 + row * 64 + ((kc ^ (row & 7)) * 8)];
            }
            __builtin_amdgcn_s_setprio(1);
            #pragma unroll
            for (int tc = 0; tc < 2; ++tc)
                a1[tc] = __builtin_amdgcn_mfma_f32_32x32x16_f16(yf1[ks], gv[tc], a1[tc], 0, 0, 0);
            __builtin_amdgcn_s_setprio(0);
        }
        asm volatile("s_waitcnt lgkmcnt(0)" ::: "memory");  // half0 tb reads done
        SB();
        #pragma unroll
        for (int tc = 0; tc < 2; ++tc) {
            const int col = 32 * tc + l31;
            #pragma unroll
            for (int q2 = 0; q2 < 4; ++q2) {
                half4 hv;
                #pragma unroll
                for (int rq = 0; rq < 4; ++rq) hv[rq] = (_Float16)a1[tc][q2 * 4 + rq];
                *(half4*)&tt[col * 32 + ((q2 ^ (col & 3)) * 8) + 4 * kh] = hv;
            }
        }
    }
    asm volatile("s_waitcnt lgkmcnt(0)" ::: "memory");
    SB();
    // GEMM2 half1: tt rows are T rows 32..63 -> global Gu k-groups 4..7
    #pragma unroll
    for (int ks2 = 0; ks2 < 2; ++ks2) {
        const int kc2 = ks2 * 2 + kh;       // 0..3 within half
        const int gkc = 4 + kc2;            // global Gu k-group
        half8 gu[2], tb[2];
        #pragma unroll
        for (int tr = 0; tr < 2; ++tr) {
            const int row = 32 * tr + l31;
            gu[tr] = *(const half8*)&Gsh[row * 64 + ((gkc ^ (row & 7)) * 8)];
        }
        #pragma unroll
        for (int tc = 0; tc < 2; ++tc) {
            const int col = 32 * tc + l31;
            tb[tc] = *(const half8*)&tt[col * 32 + ((kc2 ^ (col & 3)) * 8)];
        }
        __builtin_amdgcn_s_setprio(1);
        #pragma unroll
        for (int tr = 0; tr < 2; ++tr)
            #pragma unroll
            for (int tc = 0; tc < 2; ++tc)
                a2[tr][tc] = __builtin_amdgcn_mfma_f32_32x32x16_f16(gu[tr], tb[tc], a2[tr][tc], 0, 0, 0);
        __builtin_amdgcn_s_setprio(0);
    }

    // ---- epilogue: fp32 over the plane slot ----
    #pragma unroll
    for (int tr = 0; tr < 2; ++tr)
        #pragma unroll
        for (int tc = 0; tc < 2; ++tc)
            #pragma unroll
            for (int reg = 0; reg < 16; ++reg) {
                const int row = 32 * tr + (reg & 3) + 8 * (reg >> 2) + 4 * kh;
                yp[row * 64 + 32 * tc + l31] = a2[tr][tc][reg];
            }
}

extern "C" void kernel_launch(void* const* d_in, const int* in_sizes, int n_in,
                              void* d_out, int out_size, void* d_ws, size_t ws_size,
                              hipStream_t stream) {
    const float* x     = (const float*)d_in[0];
    const float* w     = (const float*)d_in[1];
    const float* alpha = (const float*)d_in[2];
    float* y = (float*)d_out;

    // workspace layout (bytes) — 5.4 MB total
    _Float16* w16 = (_Float16*)d_ws;                               // 1,179,648 B
    _Float16* gm  = (_Float16*)((char*)d_ws + 1179648);            // 4,194,304 B
    float4*   zp  = (float4*)((char*)d_ws + 5373952);              //     4,096 B

    static bool inited = false;
    if (!inited) {
        hipFuncSetAttribute((const void*)conv_mfma,
                            hipFuncAttributeMaxDynamicSharedMemorySize, 78336);
        inited = true;
    }

    prep_kernel  <<<dim3(18944), 256, 0, stream>>>(x, w, alpha, y, w16, gm, zp);
    conv_mfma    <<<dim3(1024),  256, 78336, stream>>>(w16, (const _Float16*)zp, y);
    solve_mfma   <<<dim3(2048),  256, 0, stream>>>(gm, y);
}